// Round 12
// baseline (1252.503 us; speedup 1.0000x reference)
//
#include <hip/hip_runtime.h>
#include <math.h>

#define NN 50000
#define NE 800000
#define F_IN 64
#define HID 128
#define HEADS 4
#define LAYERS 3

typedef __attribute__((ext_vector_type(8))) short bf16x8;
typedef __attribute__((ext_vector_type(8))) unsigned short ushort8;
typedef __attribute__((ext_vector_type(4))) float f32x4;
typedef __attribute__((ext_vector_type(4))) unsigned int u32x4;
typedef __attribute__((ext_vector_type(2))) unsigned int u32x2;

__device__ __forceinline__ float b2f(unsigned short u) {
  return __builtin_bit_cast(float, ((unsigned int)u) << 16);
}
__device__ __forceinline__ unsigned short f2bf(float f) {
  unsigned int u = __builtin_bit_cast(unsigned int, f);
  u = (u + 0x7FFFu + ((u >> 16) & 1u)) >> 16;
  return (unsigned short)u;
}
__device__ __forceinline__ float bitf(unsigned int u) {
  return __builtin_bit_cast(float, u);
}

// ---------------- CSR build ----------------

__global__ void hist_kernel(const int* __restrict__ dst, int* __restrict__ counts, int E) {
  int e = blockIdx.x * blockDim.x + threadIdx.x;
  if (e < E) atomicAdd(&counts[dst[e]], 1);
}

__global__ void scan_kernel(const int* __restrict__ counts, int* __restrict__ indptr, int n) {
  __shared__ int buf[1024];
  __shared__ int carry_s;
  int tid = threadIdx.x;
  if (tid == 0) carry_s = 0;
  __syncthreads();
  for (int base = 0; base < n; base += 1024) {
    int v = (base + tid < n) ? counts[base + tid] : 0;
    buf[tid] = v;
    __syncthreads();
    for (int off = 1; off < 1024; off <<= 1) {
      int t = (tid >= off) ? buf[tid - off] : 0;
      __syncthreads();
      buf[tid] += t;
      __syncthreads();
    }
    int incl = buf[tid];
    int total = buf[1023];
    int carry = carry_s;
    if (base + tid < n) indptr[base + tid] = carry + incl - v;
    __syncthreads();
    if (tid == 0) carry_s = carry + total;
    __syncthreads();
  }
  if (tid == 0) indptr[n] = carry_s;
}

__global__ void scatter_kernel(const int* __restrict__ src, const int* __restrict__ dst,
                               const int* __restrict__ indptr, int* __restrict__ fill,
                               int* __restrict__ srcs, int E) {
  int e = blockIdx.x * blockDim.x + threadIdx.x;
  if (e < E) {
    int d = dst[e];
    int pos = atomicAdd(&fill[d], 1);
    srcs[indptr[d] + pos] = src[e];
  }
}

// ---------------- weight prep: concat Wl|Wr, split hi/lo (separate planes), transpose ----------------
// BTh/BTl: [L][1024][128]. Row n (n<512 => Wl col n, else Wr col n-512).

__global__ void prep_w(const float* __restrict__ Wl, const float* __restrict__ Wr,
                       unsigned short* __restrict__ BTh, unsigned short* __restrict__ BTl) {
  int id = blockIdx.x * 256 + threadIdx.x;   // < LAYERS*1024*128
  int l = id >> 17;
  int rem = id & 131071;
  int n = rem >> 7;
  int k = rem & 127;
  float v = (n < 512) ? Wl[((size_t)l * 128 + k) * 512 + n]
                      : Wr[((size_t)l * 128 + k) * 512 + (n - 512)];
  unsigned short h = f2bf(v);
  unsigned short lo = f2bf(v - b2f(h));
  size_t base = (size_t)(l * 1024 + n) * 128 + k;
  BTh[base] = h;
  BTl[base] = lo;
}

// ---------------- persistent MFMA GEMM: B-hi in LDS (33.8 KB -> 4 blocks/CU), B-lo from L2 ----------------
// [xl|xr][M,1024] = Act[M,128] @ [Wl|Wr] + [bl|br]. AHL: [M][256] hi|lo interleaved.
// 1024 blocks = 8 n-tiles(128) x 128 m-groups (4 blocks/CU). Swapped mfma: lane&15 = row,
// regs = 4 consecutive cols -> 16x 8B nt stores. Bias in epilogue (VGPR budget <=128).

#define BSTR 136
#define MT_TOT ((NN + 127) / 128)

__global__ void __launch_bounds__(256, 4)
mfma_gemm_pers(const unsigned short* __restrict__ AHL,
               const unsigned short* __restrict__ BTh, const unsigned short* __restrict__ BTl,
               const float* __restrict__ bias_l, const float* __restrict__ bias_r,
               unsigned short* __restrict__ XL, unsigned short* __restrict__ XR, int M) {
  __shared__ unsigned short sBh[128 * BSTR];

  // bijective XCD swizzle (gridDim.x == 1024): XCD x gets wg = x*128 .. x*128+127
  // -> co-XCD blocks: 16 mgroups x all 8 ntiles => A panels shared in-XCD L2
  int bid = blockIdx.x;
  int wg = (bid & 7) * 128 + (bid >> 3);
  int ntile = wg & 7;
  int mgroup = wg >> 3;
  int n0 = ntile * 128;

  int tid = threadIdx.x;
  // stage B-hi panel: 128 rows x 128 ushort -> sBh[row*BSTR + col]
  {
    int row = tid >> 1, half = tid & 1;
    const unsigned short* src = BTh + (size_t)(n0 + row) * 128 + half * 64;
    unsigned short* dst = sBh + row * BSTR + half * 64;
#pragma unroll
    for (int j = 0; j < 8; ++j)
      *(ushort8*)(dst + j * 8) = *(const ushort8*)(src + j * 8);
  }
  __syncthreads();

  int wv = tid >> 6, lane = tid & 63;
  int wr = wv >> 1, wc = wv & 1;   // wr: m-half (64 rows), wc: n-half (64 cols)
  int kb2 = (lane >> 4) * 16;      // k-block byte offset within a 256B (hi) row

  // B-hi fragment LDS pointers + B-lo global byte offsets (block-constant)
  const unsigned short* pbh[4];
  unsigned int blo_off[4];
#pragma unroll
  for (int t = 0; t < 4; ++t) {
    int rb = wc * 64 + t * 16 + (lane & 15);
    pbh[t] = sBh + rb * BSTR + (lane >> 4) * 8;
    blo_off[t] = (unsigned int)((n0 + rb) * 256 + kb2);   // bytes into BTl plane
  }

  unsigned short* Xout = (ntile < 4) ? XL : XR;
  const float* bias_sel = (ntile < 4) ? bias_l : bias_r;
  int ncol0 = (n0 & 511) + wc * 64;

  for (int mt = mgroup; mt < MT_TOT; mt += 128) {
    int m0 = mt * 128;
    unsigned int aoff[4];
#pragma unroll
    for (int t = 0; t < 4; ++t) {
      int ra = m0 + wr * 64 + t * 16 + (lane & 15);
      if (ra >= M) ra = M - 1;   // clamp: garbage rows never stored
      aoff[t] = (unsigned int)(ra * 512 + kb2);   // bytes into AHL (hi|lo interleaved)
    }

    f32x4 acc[4][4];   // [fw][fa]
#pragma unroll
    for (int i = 0; i < 4; ++i)
#pragma unroll
      for (int j = 0; j < 4; ++j) acc[i][j] = (f32x4)0.f;

#pragma unroll
    for (int ks = 0; ks < 4; ++ks) {
      bf16x8 fah[4], fal[4], fbh[4], fbl[4];
#pragma unroll
      for (int t = 0; t < 4; ++t) {
        const char* p = (const char*)AHL + aoff[t] + ks * 64;
        fah[t] = *(const bf16x8*)p;
        fal[t] = *(const bf16x8*)(p + 256);
        fbl[t] = *(const bf16x8*)((const char*)BTl + blo_off[t] + ks * 64);
        fbh[t] = *(const bf16x8*)(pbh[t] + ks * 32);
      }
      // swapped: A-op = weight frag, B-op = activation frag
#pragma unroll
      for (int fw = 0; fw < 4; ++fw)
#pragma unroll
        for (int fa = 0; fa < 4; ++fa) {
          f32x4 c = acc[fw][fa];
          c = __builtin_amdgcn_mfma_f32_16x16x32_bf16(fbl[fw], fah[fa], c, 0, 0, 0);
          c = __builtin_amdgcn_mfma_f32_16x16x32_bf16(fbh[fw], fal[fa], c, 0, 0, 0);
          c = __builtin_amdgcn_mfma_f32_16x16x32_bf16(fbh[fw], fah[fa], c, 0, 0, 0);
          acc[fw][fa] = c;
        }
    }

    // epilogue: bias loaded here (keeps main-loop VGPR low); 16x 8B nt stores
    f32x4 bv[4];
#pragma unroll
    for (int t = 0; t < 4; ++t)
      bv[t] = *(const f32x4*)&bias_sel[ncol0 + t * 16 + (lane >> 4) * 4];
#pragma unroll
    for (int fa = 0; fa < 4; ++fa) {
      int row = m0 + wr * 64 + fa * 16 + (lane & 15);
      if (row < M) {
#pragma unroll
        for (int fw = 0; fw < 4; ++fw) {
          int col = ncol0 + fw * 16 + (lane >> 4) * 4;
          f32x4 v = acc[fw][fa];
          unsigned int u0 = (unsigned int)f2bf(v[0] + bv[fw][0]) |
                            ((unsigned int)f2bf(v[1] + bv[fw][1]) << 16);
          unsigned int u1 = (unsigned int)f2bf(v[2] + bv[fw][2]) |
                            ((unsigned int)f2bf(v[3] + bv[fw][3]) << 16);
          u32x2 o; o[0] = u0; o[1] = u1;
          __builtin_nontemporal_store(o, (u32x2*)&Xout[(size_t)row * 512 + col]);
        }
      }
    }
  }
}

// ---------------- fp32 tiled GEMM: C = act(A @ B + bias), optional hi/lo split output ----------------

template <int ACT, int SPLIT>
__global__ void __launch_bounds__(256)
gemm_bias(const float* __restrict__ A, const float* __restrict__ B,
          const float* __restrict__ bias, float* __restrict__ C,
          unsigned short* __restrict__ Chl,
          int M, int K, int Nc) {
  __shared__ float As[16][68];
  __shared__ float Bs[16][68];
  int tid = threadIdx.x;
  int tx = tid & 15, ty = tid >> 4;
  int m0 = blockIdx.y * 64;
  int n0 = blockIdx.x * 64;

  int arow = tid >> 2;
  int acol = (tid & 3) * 4;
  int brow = tid >> 4;
  int bcol = (tid & 15) * 4;

  float acc[4][4];
#pragma unroll
  for (int i = 0; i < 4; ++i)
#pragma unroll
    for (int j = 0; j < 4; ++j) acc[i][j] = 0.f;

  for (int k0 = 0; k0 < K; k0 += 16) {
    float4 av = make_float4(0.f, 0.f, 0.f, 0.f);
    if (m0 + arow < M) av = *(const float4*)&A[(size_t)(m0 + arow) * K + k0 + acol];
    As[acol + 0][arow] = av.x;
    As[acol + 1][arow] = av.y;
    As[acol + 2][arow] = av.z;
    As[acol + 3][arow] = av.w;
    float4 bvv = *(const float4*)&B[(size_t)(k0 + brow) * Nc + n0 + bcol];
    *(float4*)&Bs[brow][bcol] = bvv;
    __syncthreads();
#pragma unroll
    for (int k = 0; k < 16; ++k) {
      float4 a = *(const float4*)&As[k][ty * 4];
      float4 b = *(const float4*)&Bs[k][tx * 4];
      acc[0][0] += a.x * b.x; acc[0][1] += a.x * b.y; acc[0][2] += a.x * b.z; acc[0][3] += a.x * b.w;
      acc[1][0] += a.y * b.x; acc[1][1] += a.y * b.y; acc[1][2] += a.y * b.z; acc[1][3] += a.y * b.w;
      acc[2][0] += a.z * b.x; acc[2][1] += a.z * b.y; acc[2][2] += a.z * b.z; acc[2][3] += a.z * b.w;
      acc[3][0] += a.w * b.x; acc[3][1] += a.w * b.y; acc[3][2] += a.w * b.z; acc[3][3] += a.w * b.w;
    }
    __syncthreads();
  }

#pragma unroll
  for (int i = 0; i < 4; ++i) {
    int row = m0 + ty * 4 + i;
    if (row < M) {
#pragma unroll
      for (int j = 0; j < 4; ++j) {
        int col = n0 + tx * 4 + j;
        float v = acc[i][j] + bias[col];
        if (ACT) v = fmaxf(v, 0.f);
        C[(size_t)row * Nc + col] = v;
        if (SPLIT) {
          unsigned short hh = f2bf(v);
          Chl[(size_t)row * 256 + col] = hh;
          Chl[(size_t)row * 256 + 128 + col] = f2bf(v - b2f(hh));
        }
      }
    }
  }
}

// ---------------- GATv2 edge phase: 1 wave per node, no barriers, no max-tracking ----------------

__global__ void __launch_bounds__(256)
gat_aggregate(const unsigned short* __restrict__ xl, const unsigned short* __restrict__ xr,
              const int* __restrict__ indptr, const int* __restrict__ srcs,
              const float* __restrict__ att, const float* __restrict__ conv_bias,
              const float* __restrict__ h_in, float* __restrict__ h_out,
              unsigned short* __restrict__ o_hl, int write_split) {
  int node = blockIdx.x * 4 + (threadIdx.x >> 6);
  if (node >= NN) return;
  int lane = threadIdx.x & 63;
  int h = lane >> 4, g = lane & 15;
  int ch = h * 128 + g * 8;

  float a1[8], a2[8], xr8[8];
  {
    f32x4 t0 = *(const f32x4*)(att + ch);
    f32x4 t1 = *(const f32x4*)(att + ch + 4);
#pragma unroll
    for (int j = 0; j < 4; ++j) { a1[j] = 0.6f * t0[j]; a2[j] = 0.4f * t0[j]; }
#pragma unroll
    for (int j = 0; j < 4; ++j) { a1[4 + j] = 0.6f * t1[j]; a2[4 + j] = 0.4f * t1[j]; }
    u32x4 q = __builtin_nontemporal_load((const u32x4*)&xr[(size_t)node * 512 + ch]);
#pragma unroll
    for (int j = 0; j < 4; ++j) {
      xr8[2 * j] = bitf(q[j] << 16);
      xr8[2 * j + 1] = bitf(q[j] & 0xFFFF0000u);
    }
  }
  float base1 = 0.f;
#pragma unroll
  for (int j = 0; j < 8; ++j) base1 = fmaf(a1[j], xr8[j], base1);

  float acc[8];
#pragma unroll
  for (int j = 0; j < 8; ++j) acc[j] = 0.f;
  float s_run = 0.f;

  int beg = indptr[node];
  int deg = indptr[node + 1] - beg;

  for (int s0 = 0; s0 < deg; s0 += 4) {
    int sidx[4];
#pragma unroll
    for (int t = 0; t < 4; ++t) sidx[t] = (s0 + t < deg) ? srcs[beg + s0 + t] : -1;
    float xf[4][8], p[4];
#pragma unroll
    for (int t = 0; t < 4; ++t) {
      if (sidx[t] >= 0) {
        u32x4 q = *(const u32x4*)&xl[(size_t)sidx[t] * 512 + ch];
        float pp = base1;
#pragma unroll
        for (int j = 0; j < 4; ++j) {
          float e0 = bitf(q[j] << 16);
          float e1 = bitf(q[j] & 0xFFFF0000u);
          xf[t][2 * j] = e0;
          xf[t][2 * j + 1] = e1;
          float mm0 = e0 + xr8[2 * j];
          float mm1 = e1 + xr8[2 * j + 1];
          pp = fmaf(a1[2 * j], e0, pp);
          pp = fmaf(a2[2 * j], fabsf(mm0), pp);
          pp = fmaf(a1[2 * j + 1], e1, pp);
          pp = fmaf(a2[2 * j + 1], fabsf(mm1), pp);
        }
        p[t] = pp;
      } else {
        p[t] = -__builtin_inff();
#pragma unroll
        for (int j = 0; j < 8; ++j) xf[t][j] = 0.f;
      }
    }
#pragma unroll
    for (int t = 0; t < 4; ++t) {
#pragma unroll
      for (int off = 1; off < 16; off <<= 1) p[t] += __shfl_xor(p[t], off);
    }
    float w0 = __expf(p[0]);   // exp(-inf) = 0 for pad slots
    float w1 = __expf(p[1]);
    float w2 = __expf(p[2]);
    float w3 = __expf(p[3]);
    s_run += (w0 + w1) + (w2 + w3);
#pragma unroll
    for (int j = 0; j < 8; ++j) {
      float v = acc[j];
      v = fmaf(w0, xf[0][j], v);
      v = fmaf(w1, xf[1][j], v);
      v = fmaf(w2, xf[2][j], v);
      v = fmaf(w3, xf[3][j], v);
      acc[j] = v;
    }
  }

  // per-head normalize, mean over heads in-wave
  float inv = 1.f / fmaxf(s_run, 1e-16f);
  float v[8];
#pragma unroll
  for (int j = 0; j < 8; ++j) v[j] = acc[j] * inv;
#pragma unroll
  for (int j = 0; j < 8; ++j) v[j] += __shfl_xor(v[j], 16);
#pragma unroll
  for (int j = 0; j < 8; ++j) v[j] += __shfl_xor(v[j], 32);

  if (h == 0) {
    int c0 = g * 8;
    const float* hip_ = h_in + (size_t)node * 128 + c0;
    f32x4 hi0 = __builtin_nontemporal_load((const f32x4*)hip_);
    f32x4 hi1 = __builtin_nontemporal_load((const f32x4*)(hip_ + 4));
    f32x4 cb0 = *(const f32x4*)(conv_bias + c0);
    f32x4 cb1 = *(const f32x4*)(conv_bias + c0 + 4);
    float rr[8];
#pragma unroll
    for (int j = 0; j < 4; ++j) rr[j] = fmaxf(fmaf(v[j], 0.25f, cb0[j] + hi0[j]), 0.f);
#pragma unroll
    for (int j = 0; j < 4; ++j) rr[4 + j] = fmaxf(fmaf(v[4 + j], 0.25f, cb1[j] + hi1[j]), 0.f);
    f32x4 o0, o1;
#pragma unroll
    for (int j = 0; j < 4; ++j) { o0[j] = rr[j]; o1[j] = rr[4 + j]; }
    float* hop = h_out + (size_t)node * 128 + c0;
    __builtin_nontemporal_store(o0, (f32x4*)hop);
    __builtin_nontemporal_store(o1, (f32x4*)(hop + 4));
    if (write_split) {
      ushort8 hv, lv;
#pragma unroll
      for (int j = 0; j < 8; ++j) {
        unsigned short hh = f2bf(rr[j]);
        hv[j] = hh;
        lv[j] = f2bf(rr[j] - b2f(hh));
      }
      __builtin_nontemporal_store(hv, (ushort8*)&o_hl[(size_t)node * 256 + c0]);
      __builtin_nontemporal_store(lv, (ushort8*)&o_hl[(size_t)node * 256 + 128 + c0]);
    }
  }
}

// ---------------- final: score = clip(z2 @ p3_W + p3_b) ----------------

__global__ void __launch_bounds__(256)
predictor_final(const float* __restrict__ z2, const float* __restrict__ w3,
                const float* __restrict__ b3, float* __restrict__ out, int n) {
  int node = (blockIdx.x << 2) + (threadIdx.x >> 6);
  int lane = threadIdx.x & 63;
  if (node >= n) return;
  float v = z2[(size_t)node * 64 + lane] * w3[lane];
#pragma unroll
  for (int off = 32; off > 0; off >>= 1) v += __shfl_xor(v, off);
  if (lane == 0) {
    float s = v + b3[0];
    s = fminf(fmaxf(s, -15.f), 15.f);
    out[node] = s;
  }
}

// ---------------- launch ----------------

extern "C" void kernel_launch(void* const* d_in, const int* in_sizes, int n_in,
                              void* d_out, int out_size, void* d_ws, size_t ws_size,
                              hipStream_t stream) {
  const float* x     = (const float*)d_in[0];
  const int*   ei    = (const int*)d_in[1];
  const float* emb_W = (const float*)d_in[3];
  const float* emb_b = (const float*)d_in[4];
  const float* Wl    = (const float*)d_in[5];
  const float* bl    = (const float*)d_in[6];
  const float* Wr    = (const float*)d_in[7];
  const float* br    = (const float*)d_in[8];
  const float* att   = (const float*)d_in[9];
  const float* cbias = (const float*)d_in[10];
  const float* p1W   = (const float*)d_in[11];
  const float* p1b   = (const float*)d_in[12];
  const float* p2W   = (const float*)d_in[13];
  const float* p2b   = (const float*)d_in[14];
  const float* p3W   = (const float*)d_in[15];
  const float* p3b   = (const float*)d_in[16];
  float* out = (float*)d_out;

  char* ws = (char*)d_ws;
  size_t o = 0;
  float* h0 = (float*)(ws + o); o += (size_t)NN * 128 * 4;
  float* h1 = (float*)(ws + o); o += (size_t)NN * 128 * 4;
  unsigned short* h_hl = (unsigned short*)(ws + o); o += (size_t)NN * 256 * 2;
  unsigned short* xl_bf = (unsigned short*)(ws + o); o += (size_t)NN * 512 * 2;
  unsigned short* xr_bf = (unsigned short*)(ws + o); o += (size_t)NN * 512 * 2;
  unsigned short* BTh = (unsigned short*)(ws + o); o += (size_t)LAYERS * 1024 * 128 * 2;
  unsigned short* BTl = (unsigned short*)(ws + o); o += (size_t)LAYERS * 1024 * 128 * 2;
  int* indptr = (int*)(ws + o); o += (((size_t)(NN + 1) * 4) + 255) / 256 * 256;
  int* counts = (int*)(ws + o); o += (((size_t)NN * 4) + 255) / 256 * 256;
  int* srcs   = (int*)(ws + o); o += (size_t)NE * 4;

  const int* esrc = ei;
  const int* edst = ei + NE;

  // CSR build
  hipMemsetAsync(counts, 0, (size_t)NN * 4, stream);
  hist_kernel<<<(NE + 255) / 256, 256, 0, stream>>>(edst, counts, NE);
  scan_kernel<<<1, 1024, 0, stream>>>(counts, indptr, NN);
  hipMemsetAsync(counts, 0, (size_t)NN * 4, stream);
  scatter_kernel<<<(NE + 255) / 256, 256, 0, stream>>>(esrc, edst, indptr, counts, srcs, NE);

  // weight prep: concat + split (separate hi/lo planes) + transpose
  prep_w<<<(LAYERS * 1024 * 128) / 256, 256, 0, stream>>>(Wl, Wr, BTh, BTl);

  // embedding (fp32) + hi/lo split fused
  gemm_bias<1, 1><<<dim3(2, (NN + 63) / 64), 256, 0, stream>>>(
      x, emb_W, emb_b, h0, h_hl, NN, 64, 128);

  float* hc = h0;
  float* hn = h1;
  for (int l = 0; l < LAYERS; ++l) {
    mfma_gemm_pers<<<1024, 256, 0, stream>>>(
        h_hl, BTh + (size_t)l * 1024 * 128, BTl + (size_t)l * 1024 * 128,
        bl + (size_t)l * 512, br + (size_t)l * 512, xl_bf, xr_bf, NN);
    gat_aggregate<<<(NN + 3) / 4, 256, 0, stream>>>(
        xl_bf, xr_bf, indptr, srcs, att + (size_t)l * 512, cbias + (size_t)l * 128,
        hc, hn, h_hl, (l < LAYERS - 1) ? 1 : 0);
    float* t = hc; hc = hn; hn = t;
  }

  // predictor (fp32), reuse xl/xr space
  float* z1 = (float*)xl_bf;
  float* z2 = (float*)xr_bf;
  gemm_bias<1, 0><<<dim3(2, (NN + 63) / 64), 256, 0, stream>>>(
      hc, p1W, p1b, z1, (unsigned short*)0, NN, 128, 128);
  gemm_bias<1, 0><<<dim3(1, (NN + 63) / 64), 256, 0, stream>>>(
      z1, p2W, p2b, z2, (unsigned short*)0, NN, 128, 64);
  predictor_final<<<(NN + 3) / 4, 256, 0, stream>>>(z2, p3W, p3b, out, NN);
}

// Round 13
// 951.982 us; speedup vs baseline: 1.3157x; 1.3157x over previous
//
#include <hip/hip_runtime.h>
#include <math.h>

#define NN 50000
#define NE 800000
#define F_IN 64
#define HID 128
#define HEADS 4
#define LAYERS 3

typedef __attribute__((ext_vector_type(8))) short bf16x8;
typedef __attribute__((ext_vector_type(8))) unsigned short ushort8;
typedef __attribute__((ext_vector_type(4))) float f32x4;
typedef __attribute__((ext_vector_type(4))) unsigned int u32x4;

__device__ __forceinline__ float b2f(unsigned short u) {
  return __builtin_bit_cast(float, ((unsigned int)u) << 16);
}
__device__ __forceinline__ unsigned short f2bf(float f) {
  unsigned int u = __builtin_bit_cast(unsigned int, f);
  u = (u + 0x7FFFu + ((u >> 16) & 1u)) >> 16;
  return (unsigned short)u;
}
__device__ __forceinline__ float bitf(unsigned int u) {
  return __builtin_bit_cast(float, u);
}

// ---------------- CSR build ----------------

__global__ void hist_kernel(const int* __restrict__ dst, int* __restrict__ counts, int E) {
  int e = blockIdx.x * blockDim.x + threadIdx.x;
  if (e < E) atomicAdd(&counts[dst[e]], 1);
}

__global__ void scan_kernel(const int* __restrict__ counts, int* __restrict__ indptr, int n) {
  __shared__ int buf[1024];
  __shared__ int carry_s;
  int tid = threadIdx.x;
  if (tid == 0) carry_s = 0;
  __syncthreads();
  for (int base = 0; base < n; base += 1024) {
    int v = (base + tid < n) ? counts[base + tid] : 0;
    buf[tid] = v;
    __syncthreads();
    for (int off = 1; off < 1024; off <<= 1) {
      int t = (tid >= off) ? buf[tid - off] : 0;
      __syncthreads();
      buf[tid] += t;
      __syncthreads();
    }
    int incl = buf[tid];
    int total = buf[1023];
    int carry = carry_s;
    if (base + tid < n) indptr[base + tid] = carry + incl - v;
    __syncthreads();
    if (tid == 0) carry_s = carry + total;
    __syncthreads();
  }
  if (tid == 0) indptr[n] = carry_s;
}

__global__ void scatter_kernel(const int* __restrict__ src, const int* __restrict__ dst,
                               const int* __restrict__ indptr, int* __restrict__ fill,
                               int* __restrict__ srcs, int E) {
  int e = blockIdx.x * blockDim.x + threadIdx.x;
  if (e < E) {
    int d = dst[e];
    int pos = atomicAdd(&fill[d], 1);
    srcs[indptr[d] + pos] = src[e];
  }
}

// ---------------- weight prep: concat Wl|Wr, split hi/lo, transpose -> BT[L][1024][256] ----------------

__global__ void prep_w(const float* __restrict__ Wl, const float* __restrict__ Wr,
                       unsigned short* __restrict__ BT) {
  int id = blockIdx.x * 256 + threadIdx.x;   // < LAYERS*1024*128
  int l = id >> 17;
  int rem = id & 131071;
  int n = rem >> 7;
  int k = rem & 127;
  float v = (n < 512) ? Wl[((size_t)l * 128 + k) * 512 + n]
                      : Wr[((size_t)l * 128 + k) * 512 + (n - 512)];
  unsigned short h = f2bf(v);
  unsigned short lo = f2bf(v - b2f(h));
  size_t base = (size_t)(l * 1024 + n) * 256 + k;
  BT[base] = h;
  BT[base + 128] = lo;
}

// ---------------- persistent MFMA GEMM (round-7 proven form): B in LDS, 512 blocks ----------------

#define BSTRIDE 264
#define MT_TOT ((NN + 127) / 128)

__global__ void __launch_bounds__(256, 2)
mfma_gemm_pers(const unsigned short* __restrict__ AHL, const unsigned short* __restrict__ BTHL,
               const float* __restrict__ bias_l, const float* __restrict__ bias_r,
               unsigned short* __restrict__ XL, unsigned short* __restrict__ XR, int M) {
  __shared__ unsigned short sB[128 * BSTRIDE];

  // bijective XCD swizzle (gridDim.x == 512): XCD x gets wg = x*64 .. x*64+63
  int bid = blockIdx.x;
  int wg = (bid & 7) * 64 + (bid >> 3);
  int ntile = wg & 7;
  int mgroup = wg >> 3;
  int n0 = ntile * 128;

  int tid = threadIdx.x;
  // stage B panel: 128 rows x 256 ushort -> sB[row*BSTRIDE + col]
  {
    int row = tid >> 1, half = tid & 1;
    const unsigned short* src = BTHL + (size_t)(n0 + row) * 256 + half * 128;
    unsigned short* dst = sB + row * BSTRIDE + half * 128;
#pragma unroll
    for (int j = 0; j < 16; ++j)
      *(ushort8*)(dst + j * 8) = *(const ushort8*)(src + j * 8);
  }
  __syncthreads();

  int wv = tid >> 6, lane = tid & 63;
  int wr = wv >> 1, wc = wv & 1;
  int kb = (lane >> 4) * 8;

  const unsigned short* pb[4];
#pragma unroll
  for (int t = 0; t < 4; ++t)
    pb[t] = sB + (wc * 64 + t * 16 + (lane & 15)) * BSTRIDE + kb;

  float bv[4];
#pragma unroll
  for (int fn = 0; fn < 4; ++fn) {
    int col = n0 + wc * 64 + fn * 16 + (lane & 15);
    bv[fn] = (col < 512) ? bias_l[col] : bias_r[col - 512];
  }

  for (int mt = mgroup; mt < MT_TOT; mt += 64) {
    int m0 = mt * 128;
    const unsigned short* pa[4];
#pragma unroll
    for (int t = 0; t < 4; ++t) {
      int ra = m0 + wr * 64 + t * 16 + (lane & 15);
      if (ra >= M) ra = M - 1;   // clamp: garbage rows never stored
      pa[t] = AHL + (size_t)ra * 256 + kb;
    }

    f32x4 acc[4][4];
#pragma unroll
    for (int i = 0; i < 4; ++i)
#pragma unroll
      for (int j = 0; j < 4; ++j) acc[i][j] = (f32x4)0.f;

#pragma unroll
    for (int ks = 0; ks < 4; ++ks) {
      bf16x8 fah[4], fal[4], fbh[4], fbl[4];
#pragma unroll
      for (int t = 0; t < 4; ++t) {
        fah[t] = *(const bf16x8*)(pa[t] + ks * 32);
        fal[t] = *(const bf16x8*)(pa[t] + 128 + ks * 32);
      }
#pragma unroll
      for (int t = 0; t < 4; ++t) {
        fbh[t] = *(const bf16x8*)(pb[t] + ks * 32);
        fbl[t] = *(const bf16x8*)(pb[t] + 128 + ks * 32);
      }
#pragma unroll
      for (int fm = 0; fm < 4; ++fm)
#pragma unroll
        for (int fn = 0; fn < 4; ++fn) {
          f32x4 c = acc[fm][fn];
          c = __builtin_amdgcn_mfma_f32_16x16x32_bf16(fal[fm], fbh[fn], c, 0, 0, 0);
          c = __builtin_amdgcn_mfma_f32_16x16x32_bf16(fah[fm], fbl[fn], c, 0, 0, 0);
          c = __builtin_amdgcn_mfma_f32_16x16x32_bf16(fah[fm], fbh[fn], c, 0, 0, 0);
          acc[fm][fn] = c;
        }
    }

#pragma unroll
    for (int fm = 0; fm < 4; ++fm) {
      int rbase = m0 + wr * 64 + fm * 16 + (lane >> 4) * 4;
#pragma unroll
      for (int fn = 0; fn < 4; ++fn) {
        int col = n0 + wc * 64 + fn * 16 + (lane & 15);
#pragma unroll
        for (int rr = 0; rr < 4; ++rr) {
          int row = rbase + rr;
          if (row < M) {
            unsigned short o = f2bf(acc[fm][fn][rr] + bv[fn]);
            if (col < 512) XL[(size_t)row * 512 + col] = o;
            else           XR[(size_t)row * 512 + col - 512] = o;
          }
        }
      }
    }
  }
}

// ---------------- fp32 tiled GEMM: C = act(A @ B + bias), optional hi/lo split output ----------------

template <int ACT, int SPLIT>
__global__ void __launch_bounds__(256)
gemm_bias(const float* __restrict__ A, const float* __restrict__ B,
          const float* __restrict__ bias, float* __restrict__ C,
          unsigned short* __restrict__ Chl,
          int M, int K, int Nc) {
  __shared__ float As[16][68];
  __shared__ float Bs[16][68];
  int tid = threadIdx.x;
  int tx = tid & 15, ty = tid >> 4;
  int m0 = blockIdx.y * 64;
  int n0 = blockIdx.x * 64;

  int arow = tid >> 2;
  int acol = (tid & 3) * 4;
  int brow = tid >> 4;
  int bcol = (tid & 15) * 4;

  float acc[4][4];
#pragma unroll
  for (int i = 0; i < 4; ++i)
#pragma unroll
    for (int j = 0; j < 4; ++j) acc[i][j] = 0.f;

  for (int k0 = 0; k0 < K; k0 += 16) {
    float4 av = make_float4(0.f, 0.f, 0.f, 0.f);
    if (m0 + arow < M) av = *(const float4*)&A[(size_t)(m0 + arow) * K + k0 + acol];
    As[acol + 0][arow] = av.x;
    As[acol + 1][arow] = av.y;
    As[acol + 2][arow] = av.z;
    As[acol + 3][arow] = av.w;
    float4 bvv = *(const float4*)&B[(size_t)(k0 + brow) * Nc + n0 + bcol];
    *(float4*)&Bs[brow][bcol] = bvv;
    __syncthreads();
#pragma unroll
    for (int k = 0; k < 16; ++k) {
      float4 a = *(const float4*)&As[k][ty * 4];
      float4 b = *(const float4*)&Bs[k][tx * 4];
      acc[0][0] += a.x * b.x; acc[0][1] += a.x * b.y; acc[0][2] += a.x * b.z; acc[0][3] += a.x * b.w;
      acc[1][0] += a.y * b.x; acc[1][1] += a.y * b.y; acc[1][2] += a.y * b.z; acc[1][3] += a.y * b.w;
      acc[2][0] += a.z * b.x; acc[2][1] += a.z * b.y; acc[2][2] += a.z * b.z; acc[2][3] += a.z * b.w;
      acc[3][0] += a.w * b.x; acc[3][1] += a.w * b.y; acc[3][2] += a.w * b.z; acc[3][3] += a.w * b.w;
    }
    __syncthreads();
  }

#pragma unroll
  for (int i = 0; i < 4; ++i) {
    int row = m0 + ty * 4 + i;
    if (row < M) {
#pragma unroll
      for (int j = 0; j < 4; ++j) {
        int col = n0 + tx * 4 + j;
        float v = acc[i][j] + bias[col];
        if (ACT) v = fmaxf(v, 0.f);
        C[(size_t)row * Nc + col] = v;
        if (SPLIT) {
          unsigned short hh = f2bf(v);
          Chl[(size_t)row * 256 + col] = hh;
          Chl[(size_t)row * 256 + 128 + col] = f2bf(v - b2f(hh));
        }
      }
    }
  }
}

// ---------------- GATv2 edge phase: 1 wave per node, 8 edges in flight ----------------
// lane = h*16+g, ch = h*128+g*8. leaky(m)*att = (0.6att)m + (0.4att)|m|.
// 8 gathers issued per iteration -> 2x memory-level parallelism vs round 7.

__global__ void __launch_bounds__(256)
gat_aggregate(const unsigned short* __restrict__ xl, const unsigned short* __restrict__ xr,
              const int* __restrict__ indptr, const int* __restrict__ srcs,
              const float* __restrict__ att, const float* __restrict__ conv_bias,
              const float* __restrict__ h_in, float* __restrict__ h_out,
              unsigned short* __restrict__ o_hl, int write_split) {
  int node = blockIdx.x * 4 + (threadIdx.x >> 6);
  if (node >= NN) return;
  int lane = threadIdx.x & 63;
  int h = lane >> 4, g = lane & 15;
  int ch = h * 128 + g * 8;

  float a1[8], a2[8], xr8[8];
  {
    f32x4 t0 = *(const f32x4*)(att + ch);
    f32x4 t1 = *(const f32x4*)(att + ch + 4);
#pragma unroll
    for (int j = 0; j < 4; ++j) { a1[j] = 0.6f * t0[j]; a2[j] = 0.4f * t0[j]; }
#pragma unroll
    for (int j = 0; j < 4; ++j) { a1[4 + j] = 0.6f * t1[j]; a2[4 + j] = 0.4f * t1[j]; }
    u32x4 q = __builtin_nontemporal_load((const u32x4*)&xr[(size_t)node * 512 + ch]);
#pragma unroll
    for (int j = 0; j < 4; ++j) {
      xr8[2 * j] = bitf(q[j] << 16);
      xr8[2 * j + 1] = bitf(q[j] & 0xFFFF0000u);
    }
  }
  float base1 = 0.f;
#pragma unroll
  for (int j = 0; j < 8; ++j) base1 = fmaf(a1[j], xr8[j], base1);

  float acc[8];
#pragma unroll
  for (int j = 0; j < 8; ++j) acc[j] = 0.f;
  float s_run = 0.f;

  int beg = indptr[node];
  int deg = indptr[node + 1] - beg;

  for (int s0 = 0; s0 < deg; s0 += 8) {
    // issue all 8 gathers first (raw u32x4 regs) -> 8 loads in flight
    u32x4 q[8];
    int valid = deg - s0;          // >=1
#pragma unroll
    for (int t = 0; t < 8; ++t) {
      int slot = s0 + t;
      int s = (slot < deg) ? srcs[beg + slot] : srcs[beg];  // pad re-reads edge 0
      q[t] = *(const u32x4*)&xl[(size_t)s * 512 + ch];
    }
    // scores
    float p[8];
#pragma unroll
    for (int t = 0; t < 8; ++t) {
      float pp = base1;
#pragma unroll
      for (int j = 0; j < 4; ++j) {
        float e0 = bitf(q[t][j] << 16);
        float e1 = bitf(q[t][j] & 0xFFFF0000u);
        float mm0 = e0 + xr8[2 * j];
        float mm1 = e1 + xr8[2 * j + 1];
        pp = fmaf(a1[2 * j], e0, pp);
        pp = fmaf(a2[2 * j], fabsf(mm0), pp);
        pp = fmaf(a1[2 * j + 1], e1, pp);
        pp = fmaf(a2[2 * j + 1], fabsf(mm1), pp);
      }
      p[t] = pp;
    }
#pragma unroll
    for (int t = 0; t < 8; ++t) {
#pragma unroll
      for (int off = 1; off < 16; off <<= 1) p[t] += __shfl_xor(p[t], off);
    }
    float w[8];
#pragma unroll
    for (int t = 0; t < 8; ++t)
      w[t] = (t < valid) ? __expf(p[t]) : 0.f;   // pad slots contribute 0
#pragma unroll
    for (int t = 0; t < 8; ++t) s_run += w[t];
#pragma unroll
    for (int j = 0; j < 8; ++j) {
      float v = acc[j];
#pragma unroll
      for (int t = 0; t < 8; ++t) {
        int jj = j >> 1;
        float e = (j & 1) ? bitf(q[t][jj] & 0xFFFF0000u) : bitf(q[t][jj] << 16);
        v = fmaf(w[t], e, v);
      }
      acc[j] = v;
    }
  }

  // per-head normalize, mean over heads in-wave
  float inv = 1.f / fmaxf(s_run, 1e-16f);
  float v[8];
#pragma unroll
  for (int j = 0; j < 8; ++j) v[j] = acc[j] * inv;
#pragma unroll
  for (int j = 0; j < 8; ++j) v[j] += __shfl_xor(v[j], 16);
#pragma unroll
  for (int j = 0; j < 8; ++j) v[j] += __shfl_xor(v[j], 32);

  if (h == 0) {
    int c0 = g * 8;
    const float* hip_ = h_in + (size_t)node * 128 + c0;
    f32x4 hi0 = __builtin_nontemporal_load((const f32x4*)hip_);
    f32x4 hi1 = __builtin_nontemporal_load((const f32x4*)(hip_ + 4));
    f32x4 cb0 = *(const f32x4*)(conv_bias + c0);
    f32x4 cb1 = *(const f32x4*)(conv_bias + c0 + 4);
    float rr[8];
#pragma unroll
    for (int j = 0; j < 4; ++j) rr[j] = fmaxf(fmaf(v[j], 0.25f, cb0[j] + hi0[j]), 0.f);
#pragma unroll
    for (int j = 0; j < 4; ++j) rr[4 + j] = fmaxf(fmaf(v[4 + j], 0.25f, cb1[j] + hi1[j]), 0.f);
    f32x4 o0, o1;
#pragma unroll
    for (int j = 0; j < 4; ++j) { o0[j] = rr[j]; o1[j] = rr[4 + j]; }
    float* hop = h_out + (size_t)node * 128 + c0;
    __builtin_nontemporal_store(o0, (f32x4*)hop);
    __builtin_nontemporal_store(o1, (f32x4*)(hop + 4));
    if (write_split) {
      ushort8 hv, lv;
#pragma unroll
      for (int j = 0; j < 8; ++j) {
        unsigned short hh = f2bf(rr[j]);
        hv[j] = hh;
        lv[j] = f2bf(rr[j] - b2f(hh));
      }
      __builtin_nontemporal_store(hv, (ushort8*)&o_hl[(size_t)node * 256 + c0]);
      __builtin_nontemporal_store(lv, (ushort8*)&o_hl[(size_t)node * 256 + 128 + c0]);
    }
  }
}

// ---------------- final: score = clip(z2 @ p3_W + p3_b) ----------------

__global__ void __launch_bounds__(256)
predictor_final(const float* __restrict__ z2, const float* __restrict__ w3,
                const float* __restrict__ b3, float* __restrict__ out, int n) {
  int node = (blockIdx.x << 2) + (threadIdx.x >> 6);
  int lane = threadIdx.x & 63;
  if (node >= n) return;
  float v = z2[(size_t)node * 64 + lane] * w3[lane];
#pragma unroll
  for (int off = 32; off > 0; off >>= 1) v += __shfl_xor(v, off);
  if (lane == 0) {
    float s = v + b3[0];
    s = fminf(fmaxf(s, -15.f), 15.f);
    out[node] = s;
  }
}

// ---------------- launch ----------------

extern "C" void kernel_launch(void* const* d_in, const int* in_sizes, int n_in,
                              void* d_out, int out_size, void* d_ws, size_t ws_size,
                              hipStream_t stream) {
  const float* x     = (const float*)d_in[0];
  const int*   ei    = (const int*)d_in[1];
  const float* emb_W = (const float*)d_in[3];
  const float* emb_b = (const float*)d_in[4];
  const float* Wl    = (const float*)d_in[5];
  const float* bl    = (const float*)d_in[6];
  const float* Wr    = (const float*)d_in[7];
  const float* br    = (const float*)d_in[8];
  const float* att   = (const float*)d_in[9];
  const float* cbias = (const float*)d_in[10];
  const float* p1W   = (const float*)d_in[11];
  const float* p1b   = (const float*)d_in[12];
  const float* p2W   = (const float*)d_in[13];
  const float* p2b   = (const float*)d_in[14];
  const float* p3W   = (const float*)d_in[15];
  const float* p3b   = (const float*)d_in[16];
  float* out = (float*)d_out;

  char* ws = (char*)d_ws;
  size_t o = 0;
  float* h0 = (float*)(ws + o); o += (size_t)NN * 128 * 4;
  float* h1 = (float*)(ws + o); o += (size_t)NN * 128 * 4;
  unsigned short* h_hl = (unsigned short*)(ws + o); o += (size_t)NN * 256 * 2;
  unsigned short* xl_bf = (unsigned short*)(ws + o); o += (size_t)NN * 512 * 2;
  unsigned short* xr_bf = (unsigned short*)(ws + o); o += (size_t)NN * 512 * 2;
  unsigned short* BT = (unsigned short*)(ws + o); o += (size_t)LAYERS * 1024 * 256 * 2;
  int* indptr = (int*)(ws + o); o += (((size_t)(NN + 1) * 4) + 255) / 256 * 256;
  int* counts = (int*)(ws + o); o += (((size_t)NN * 4) + 255) / 256 * 256;
  int* srcs   = (int*)(ws + o); o += (size_t)NE * 4;

  const int* esrc = ei;
  const int* edst = ei + NE;

  // CSR build
  hipMemsetAsync(counts, 0, (size_t)NN * 4, stream);
  hist_kernel<<<(NE + 255) / 256, 256, 0, stream>>>(edst, counts, NE);
  scan_kernel<<<1, 1024, 0, stream>>>(counts, indptr, NN);
  hipMemsetAsync(counts, 0, (size_t)NN * 4, stream);
  scatter_kernel<<<(NE + 255) / 256, 256, 0, stream>>>(esrc, edst, indptr, counts, srcs, NE);

  // weight prep: concat + split + transpose
  prep_w<<<(LAYERS * 1024 * 128) / 256, 256, 0, stream>>>(Wl, Wr, BT);

  // embedding (fp32) + hi/lo split fused
  gemm_bias<1, 1><<<dim3(2, (NN + 63) / 64), 256, 0, stream>>>(
      x, emb_W, emb_b, h0, h_hl, NN, 64, 128);

  float* hc = h0;
  float* hn = h1;
  for (int l = 0; l < LAYERS; ++l) {
    mfma_gemm_pers<<<512, 256, 0, stream>>>(
        h_hl, BT + (size_t)l * 1024 * 256,
        bl + (size_t)l * 512, br + (size_t)l * 512, xl_bf, xr_bf, NN);
    gat_aggregate<<<(NN + 3) / 4, 256, 0, stream>>>(
        xl_bf, xr_bf, indptr, srcs, att + (size_t)l * 512, cbias + (size_t)l * 128,
        hc, hn, h_hl, (l < LAYERS - 1) ? 1 : 0);
    float* t = hc; hc = hn; hn = t;
  }

  // predictor (fp32), reuse xl/xr space
  float* z1 = (float*)xl_bf;
  float* z2 = (float*)xr_bf;
  gemm_bias<1, 0><<<dim3(2, (NN + 63) / 64), 256, 0, stream>>>(
      hc, p1W, p1b, z1, (unsigned short*)0, NN, 128, 128);
  gemm_bias<1, 0><<<dim3(1, (NN + 63) / 64), 256, 0, stream>>>(
      z1, p2W, p2b, z2, (unsigned short*)0, NN, 128, 64);
  predictor_final<<<(NN + 3) / 4, 256, 0, stream>>>(z2, p3W, p3b, out, NN);
}

// Round 14
// 863.866 us; speedup vs baseline: 1.4499x; 1.1020x over previous
//
#include <hip/hip_runtime.h>
#include <math.h>

#define NN 50000
#define NE 800000
#define F_IN 64
#define HID 128
#define HEADS 4
#define LAYERS 3

typedef __attribute__((ext_vector_type(8))) short bf16x8;
typedef __attribute__((ext_vector_type(8))) unsigned short ushort8;
typedef __attribute__((ext_vector_type(4))) float f32x4;
typedef __attribute__((ext_vector_type(4))) unsigned int u32x4;
typedef __attribute__((ext_vector_type(2))) unsigned int u32x2;

__device__ __forceinline__ float b2f(unsigned short u) {
  return __builtin_bit_cast(float, ((unsigned int)u) << 16);
}
__device__ __forceinline__ unsigned short f2bf(float f) {
  unsigned int u = __builtin_bit_cast(unsigned int, f);
  u = (u + 0x7FFFu + ((u >> 16) & 1u)) >> 16;
  return (unsigned short)u;
}
__device__ __forceinline__ float bitf(unsigned int u) {
  return __builtin_bit_cast(float, u);
}

__device__ __forceinline__ void gload16(const void* g, void* l) {
  __builtin_amdgcn_global_load_lds(
      (const __attribute__((address_space(1))) unsigned int*)g,
      (__attribute__((address_space(3))) unsigned int*)l, 16, 0, 0);
}

// ---------------- CSR build ----------------

__global__ void hist_kernel(const int* __restrict__ dst, int* __restrict__ counts, int E) {
  int e = blockIdx.x * blockDim.x + threadIdx.x;
  if (e < E) atomicAdd(&counts[dst[e]], 1);
}

__global__ void scan_kernel(const int* __restrict__ counts, int* __restrict__ indptr, int n) {
  __shared__ int buf[1024];
  __shared__ int carry_s;
  int tid = threadIdx.x;
  if (tid == 0) carry_s = 0;
  __syncthreads();
  for (int base = 0; base < n; base += 1024) {
    int v = (base + tid < n) ? counts[base + tid] : 0;
    buf[tid] = v;
    __syncthreads();
    for (int off = 1; off < 1024; off <<= 1) {
      int t = (tid >= off) ? buf[tid - off] : 0;
      __syncthreads();
      buf[tid] += t;
      __syncthreads();
    }
    int incl = buf[tid];
    int total = buf[1023];
    int carry = carry_s;
    if (base + tid < n) indptr[base + tid] = carry + incl - v;
    __syncthreads();
    if (tid == 0) carry_s = carry + total;
    __syncthreads();
  }
  if (tid == 0) indptr[n] = carry_s;
}

__global__ void scatter_kernel(const int* __restrict__ src, const int* __restrict__ dst,
                               const int* __restrict__ indptr, int* __restrict__ fill,
                               int* __restrict__ srcs, int E) {
  int e = blockIdx.x * blockDim.x + threadIdx.x;
  if (e < E) {
    int d = dst[e];
    int pos = atomicAdd(&fill[d], 1);
    srcs[indptr[d] + pos] = src[e];
  }
}

// ---------------- weight prep: concat Wl|Wr, split hi/lo, transpose -> BT[L][1024][256] ----------------

__global__ void prep_w(const float* __restrict__ Wl, const float* __restrict__ Wr,
                       unsigned short* __restrict__ BT) {
  int id = blockIdx.x * 256 + threadIdx.x;   // < LAYERS*1024*128
  int l = id >> 17;
  int rem = id & 131071;
  int n = rem >> 7;
  int k = rem & 127;
  float v = (n < 512) ? Wl[((size_t)l * 128 + k) * 512 + n]
                      : Wr[((size_t)l * 128 + k) * 512 + (n - 512)];
  unsigned short h = f2bf(v);
  unsigned short lo = f2bf(v - b2f(h));
  size_t base = (size_t)(l * 1024 + n) * 256 + k;
  BT[base] = h;
  BT[base + 128] = lo;
}

// ---------------- MFMA GEMM: A via global_load_lds double-buffer, B in registers ----------------
// [xl|xr][M,1024] = Act[M,128] @ [Wl|Wr] + [bl|br]. AHL: [M][256] ushorts (hi128|lo128)/row.
// 512 blocks = 8 ntiles(128 cols) x 64 mgroups; BM=64 (full K per tile = 32KB), LDS 2x32KB.
// Per wave: 32-col B slice in regs (16x bf16x8), 96 MFMA + 32 swizzled ds_read_b128 per tile.
// XOR swizzle: LDS row r slot s holds global slot s^(r&7); write via pre-swizzled SOURCE addr
// (global_load_lds dest is linear), read with same XOR -> 2-way banks (free).

#define MT64 ((NN + 63) / 64)

__global__ void __launch_bounds__(256)
mfma_gemm_pers(const unsigned short* __restrict__ AHL, const unsigned short* __restrict__ BT,
               const float* __restrict__ bias_l, const float* __restrict__ bias_r,
               unsigned short* __restrict__ XL, unsigned short* __restrict__ XR, int M) {
  __shared__ unsigned short sA[2 * 16384];   // 2 x (64 rows x 256 ushorts)

  // bijective XCD swizzle (gridDim.x == 512): XCD x gets wg = x*64..x*64+63 (ntile fastest)
  int bid = blockIdx.x;
  int wg = (bid & 7) * 64 + (bid >> 3);
  int ntile = wg & 7;
  int mgroup = wg >> 3;
  int n0 = ntile * 128;

  int T = threadIdx.x;
  int wv = T >> 6, lane = T & 63;
  int r15 = lane & 15;
  int kslot = lane >> 4;   // 0..3
  int rx = lane & 7;

  // staging constants: thread covers LDS row (R*8 + T/32), slot T&31; source slot XOR'd
  int srow = T >> 5;                       // 0..7
  int sw16 = (T & 31) ^ (srow & 7);        // pre-swizzled source slot (row&7 == srow&7)

  // B slice in registers: cols n0+wv*32 .. +32, full K, hi+lo
  bf16x8 wbh[4][2], wbl[4][2];   // [ks][fw]
#pragma unroll
  for (int ks = 0; ks < 4; ++ks)
#pragma unroll
    for (int fw = 0; fw < 2; ++fw) {
      int row = n0 + wv * 32 + fw * 16 + r15;
      size_t idx = (size_t)row * 256 + ks * 32 + kslot * 8;
      wbh[ks][fw] = *(const bf16x8*)&BT[idx];
      wbl[ks][fw] = *(const bf16x8*)&BT[idx + 128];
    }

  unsigned short* Xout = (ntile < 4) ? XL : XR;
  const float* bias_sel = (ntile < 4) ? bias_l : bias_r;
  int ncol0 = (n0 & 511) + wv * 32;
  f32x4 bv[2];
#pragma unroll
  for (int fw = 0; fw < 2; ++fw)
    bv[fw] = *(const f32x4*)&bias_sel[ncol0 + fw * 16 + kslot * 4];

  // A-frag LDS ushort offsets (within a buffer), per fa/ks/plane — swizzled
  // hi slot = ks*4+kslot, lo slot = 16+ks*4+kslot; byte = row*512 + (slot^rx)*16
  int abase[4];
#pragma unroll
  for (int fa = 0; fa < 4; ++fa) abase[fa] = (fa * 16 + r15) * 256;

  // prologue: stage first tile into buf 0
  {
    int m0 = mgroup * 64;
#pragma unroll
    for (int R = 0; R < 8; ++R) {
      int grow = m0 + R * 8 + srow;
      if (grow >= M) grow = M - 1;
      gload16(AHL + (size_t)grow * 256 + sw16 * 8, sA + R * 2048 + wv * 512);
    }
  }
  __syncthreads();

  int cur = 0;
  for (int mt = mgroup; mt < MT64; mt += 64) {
    int m0 = mt * 64;
    // issue prefetch of next tile into other buffer (DMA overlaps MFMA below)
    int nmt = mt + 64;
    if (nmt < MT64) {
      int nm0 = nmt * 64;
      int obuf = (cur ^ 1) * 16384;
#pragma unroll
      for (int R = 0; R < 8; ++R) {
        int grow = nm0 + R * 8 + srow;
        if (grow >= M) grow = M - 1;
        gload16(AHL + (size_t)grow * 256 + sw16 * 8, sA + obuf + R * 2048 + wv * 512);
      }
    }

    const unsigned short* Ab = sA + cur * 16384;
    f32x4 acc[2][4];   // [fw][fa]
#pragma unroll
    for (int i = 0; i < 2; ++i)
#pragma unroll
      for (int j = 0; j < 4; ++j) acc[i][j] = (f32x4)0.f;

#pragma unroll
    for (int ks = 0; ks < 4; ++ks) {
      int shi = ((ks * 4 + kslot) ^ rx) * 8;
      int slo = ((16 + ks * 4 + kslot) ^ rx) * 8;
      bf16x8 fah[4], fal[4];
#pragma unroll
      for (int fa = 0; fa < 4; ++fa) {
        fah[fa] = *(const bf16x8*)&Ab[abase[fa] + shi];
        fal[fa] = *(const bf16x8*)&Ab[abase[fa] + slo];
      }
#pragma unroll
      for (int fw = 0; fw < 2; ++fw)
#pragma unroll
        for (int fa = 0; fa < 4; ++fa) {
          f32x4 c = acc[fw][fa];
          c = __builtin_amdgcn_mfma_f32_16x16x32_bf16(wbl[ks][fw], fah[fa], c, 0, 0, 0);
          c = __builtin_amdgcn_mfma_f32_16x16x32_bf16(wbh[ks][fw], fal[fa], c, 0, 0, 0);
          c = __builtin_amdgcn_mfma_f32_16x16x32_bf16(wbh[ks][fw], fah[fa], c, 0, 0, 0);
          acc[fw][fa] = c;
        }
    }

    // epilogue: swapped layout -> lane&15 = row, regs = 4 consecutive cols; 8x 8B stores
#pragma unroll
    for (int fa = 0; fa < 4; ++fa) {
      int row = m0 + fa * 16 + r15;
      if (row < M) {
#pragma unroll
        for (int fw = 0; fw < 2; ++fw) {
          int col = ncol0 + fw * 16 + kslot * 4;
          f32x4 v = acc[fw][fa];
          unsigned int u0 = (unsigned int)f2bf(v[0] + bv[fw][0]) |
                            ((unsigned int)f2bf(v[1] + bv[fw][1]) << 16);
          unsigned int u1 = (unsigned int)f2bf(v[2] + bv[fw][2]) |
                            ((unsigned int)f2bf(v[3] + bv[fw][3]) << 16);
          u32x2 o; o[0] = u0; o[1] = u1;
          *(u32x2*)&Xout[(size_t)row * 512 + col] = o;
        }
      }
    }
    __syncthreads();   // drains prefetch DMA + guards buffer reuse
    cur ^= 1;
  }
}

// ---------------- fp32 tiled GEMM: C = act(A @ B + bias), optional hi/lo split output ----------------

template <int ACT, int SPLIT>
__global__ void __launch_bounds__(256)
gemm_bias(const float* __restrict__ A, const float* __restrict__ B,
          const float* __restrict__ bias, float* __restrict__ C,
          unsigned short* __restrict__ Chl,
          int M, int K, int Nc) {
  __shared__ float As[16][68];
  __shared__ float Bs[16][68];
  int tid = threadIdx.x;
  int tx = tid & 15, ty = tid >> 4;
  int m0 = blockIdx.y * 64;
  int n0 = blockIdx.x * 64;

  int arow = tid >> 2;
  int acol = (tid & 3) * 4;
  int brow = tid >> 4;
  int bcol = (tid & 15) * 4;

  float acc[4][4];
#pragma unroll
  for (int i = 0; i < 4; ++i)
#pragma unroll
    for (int j = 0; j < 4; ++j) acc[i][j] = 0.f;

  for (int k0 = 0; k0 < K; k0 += 16) {
    float4 av = make_float4(0.f, 0.f, 0.f, 0.f);
    if (m0 + arow < M) av = *(const float4*)&A[(size_t)(m0 + arow) * K + k0 + acol];
    As[acol + 0][arow] = av.x;
    As[acol + 1][arow] = av.y;
    As[acol + 2][arow] = av.z;
    As[acol + 3][arow] = av.w;
    float4 bvv = *(const float4*)&B[(size_t)(k0 + brow) * Nc + n0 + bcol];
    *(float4*)&Bs[brow][bcol] = bvv;
    __syncthreads();
#pragma unroll
    for (int k = 0; k < 16; ++k) {
      float4 a = *(const float4*)&As[k][ty * 4];
      float4 b = *(const float4*)&Bs[k][tx * 4];
      acc[0][0] += a.x * b.x; acc[0][1] += a.x * b.y; acc[0][2] += a.x * b.z; acc[0][3] += a.x * b.w;
      acc[1][0] += a.y * b.x; acc[1][1] += a.y * b.y; acc[1][2] += a.y * b.z; acc[1][3] += a.y * b.w;
      acc[2][0] += a.z * b.x; acc[2][1] += a.z * b.y; acc[2][2] += a.z * b.z; acc[2][3] += a.z * b.w;
      acc[3][0] += a.w * b.x; acc[3][1] += a.w * b.y; acc[3][2] += a.w * b.z; acc[3][3] += a.w * b.w;
    }
    __syncthreads();
  }

#pragma unroll
  for (int i = 0; i < 4; ++i) {
    int row = m0 + ty * 4 + i;
    if (row < M) {
#pragma unroll
      for (int j = 0; j < 4; ++j) {
        int col = n0 + tx * 4 + j;
        float v = acc[i][j] + bias[col];
        if (ACT) v = fmaxf(v, 0.f);
        C[(size_t)row * Nc + col] = v;
        if (SPLIT) {
          unsigned short hh = f2bf(v);
          Chl[(size_t)row * 256 + col] = hh;
          Chl[(size_t)row * 256 + 128 + col] = f2bf(v - b2f(hh));
        }
      }
    }
  }
}

// ---------------- GATv2 edge phase: 1 wave per node, 8 edges in flight (round-13 form) ----------------

__global__ void __launch_bounds__(256)
gat_aggregate(const unsigned short* __restrict__ xl, const unsigned short* __restrict__ xr,
              const int* __restrict__ indptr, const int* __restrict__ srcs,
              const float* __restrict__ att, const float* __restrict__ conv_bias,
              const float* __restrict__ h_in, float* __restrict__ h_out,
              unsigned short* __restrict__ o_hl, int write_split) {
  int node = blockIdx.x * 4 + (threadIdx.x >> 6);
  if (node >= NN) return;
  int lane = threadIdx.x & 63;
  int h = lane >> 4, g = lane & 15;
  int ch = h * 128 + g * 8;

  float a1[8], a2[8], xr8[8];
  {
    f32x4 t0 = *(const f32x4*)(att + ch);
    f32x4 t1 = *(const f32x4*)(att + ch + 4);
#pragma unroll
    for (int j = 0; j < 4; ++j) { a1[j] = 0.6f * t0[j]; a2[j] = 0.4f * t0[j]; }
#pragma unroll
    for (int j = 0; j < 4; ++j) { a1[4 + j] = 0.6f * t1[j]; a2[4 + j] = 0.4f * t1[j]; }
    u32x4 q = __builtin_nontemporal_load((const u32x4*)&xr[(size_t)node * 512 + ch]);
#pragma unroll
    for (int j = 0; j < 4; ++j) {
      xr8[2 * j] = bitf(q[j] << 16);
      xr8[2 * j + 1] = bitf(q[j] & 0xFFFF0000u);
    }
  }
  float base1 = 0.f;
#pragma unroll
  for (int j = 0; j < 8; ++j) base1 = fmaf(a1[j], xr8[j], base1);

  float acc[8];
#pragma unroll
  for (int j = 0; j < 8; ++j) acc[j] = 0.f;
  float s_run = 0.f;

  int beg = indptr[node];
  int deg = indptr[node + 1] - beg;

  for (int s0 = 0; s0 < deg; s0 += 8) {
    u32x4 q[8];
    int valid = deg - s0;
#pragma unroll
    for (int t = 0; t < 8; ++t) {
      int slot = s0 + t;
      int s = (slot < deg) ? srcs[beg + slot] : srcs[beg];
      q[t] = *(const u32x4*)&xl[(size_t)s * 512 + ch];
    }
    float p[8];
#pragma unroll
    for (int t = 0; t < 8; ++t) {
      float pp = base1;
#pragma unroll
      for (int j = 0; j < 4; ++j) {
        float e0 = bitf(q[t][j] << 16);
        float e1 = bitf(q[t][j] & 0xFFFF0000u);
        float mm0 = e0 + xr8[2 * j];
        float mm1 = e1 + xr8[2 * j + 1];
        pp = fmaf(a1[2 * j], e0, pp);
        pp = fmaf(a2[2 * j], fabsf(mm0), pp);
        pp = fmaf(a1[2 * j + 1], e1, pp);
        pp = fmaf(a2[2 * j + 1], fabsf(mm1), pp);
      }
      p[t] = pp;
    }
#pragma unroll
    for (int t = 0; t < 8; ++t) {
#pragma unroll
      for (int off = 1; off < 16; off <<= 1) p[t] += __shfl_xor(p[t], off);
    }
    float w[8];
#pragma unroll
    for (int t = 0; t < 8; ++t)
      w[t] = (t < valid) ? __expf(p[t]) : 0.f;
#pragma unroll
    for (int t = 0; t < 8; ++t) s_run += w[t];
#pragma unroll
    for (int j = 0; j < 8; ++j) {
      float v = acc[j];
#pragma unroll
      for (int t = 0; t < 8; ++t) {
        int jj = j >> 1;
        float e = (j & 1) ? bitf(q[t][jj] & 0xFFFF0000u) : bitf(q[t][jj] << 16);
        v = fmaf(w[t], e, v);
      }
      acc[j] = v;
    }
  }

  float inv = 1.f / fmaxf(s_run, 1e-16f);
  float v[8];
#pragma unroll
  for (int j = 0; j < 8; ++j) v[j] = acc[j] * inv;
#pragma unroll
  for (int j = 0; j < 8; ++j) v[j] += __shfl_xor(v[j], 16);
#pragma unroll
  for (int j = 0; j < 8; ++j) v[j] += __shfl_xor(v[j], 32);

  if (h == 0) {
    int c0 = g * 8;
    const float* hip_ = h_in + (size_t)node * 128 + c0;
    f32x4 hi0 = __builtin_nontemporal_load((const f32x4*)hip_);
    f32x4 hi1 = __builtin_nontemporal_load((const f32x4*)(hip_ + 4));
    f32x4 cb0 = *(const f32x4*)(conv_bias + c0);
    f32x4 cb1 = *(const f32x4*)(conv_bias + c0 + 4);
    float rr[8];
#pragma unroll
    for (int j = 0; j < 4; ++j) rr[j] = fmaxf(fmaf(v[j], 0.25f, cb0[j] + hi0[j]), 0.f);
#pragma unroll
    for (int j = 0; j < 4; ++j) rr[4 + j] = fmaxf(fmaf(v[4 + j], 0.25f, cb1[j] + hi1[j]), 0.f);
    f32x4 o0, o1;
#pragma unroll
    for (int j = 0; j < 4; ++j) { o0[j] = rr[j]; o1[j] = rr[4 + j]; }
    float* hop = h_out + (size_t)node * 128 + c0;
    __builtin_nontemporal_store(o0, (f32x4*)hop);
    __builtin_nontemporal_store(o1, (f32x4*)(hop + 4));
    if (write_split) {
      ushort8 hv, lv;
#pragma unroll
      for (int j = 0; j < 8; ++j) {
        unsigned short hh = f2bf(rr[j]);
        hv[j] = hh;
        lv[j] = f2bf(rr[j] - b2f(hh));
      }
      __builtin_nontemporal_store(hv, (ushort8*)&o_hl[(size_t)node * 256 + c0]);
      __builtin_nontemporal_store(lv, (ushort8*)&o_hl[(size_t)node * 256 + 128 + c0]);
    }
  }
}

// ---------------- final: score = clip(z2 @ p3_W + p3_b) ----------------

__global__ void __launch_bounds__(256)
predictor_final(const float* __restrict__ z2, const float* __restrict__ w3,
                const float* __restrict__ b3, float* __restrict__ out, int n) {
  int node = (blockIdx.x << 2) + (threadIdx.x >> 6);
  int lane = threadIdx.x & 63;
  if (node >= n) return;
  float v = z2[(size_t)node * 64 + lane] * w3[lane];
#pragma unroll
  for (int off = 32; off > 0; off >>= 1) v += __shfl_xor(v, off);
  if (lane == 0) {
    float s = v + b3[0];
    s = fminf(fmaxf(s, -15.f), 15.f);
    out[node] = s;
  }
}

// ---------------- launch ----------------

extern "C" void kernel_launch(void* const* d_in, const int* in_sizes, int n_in,
                              void* d_out, int out_size, void* d_ws, size_t ws_size,
                              hipStream_t stream) {
  const float* x     = (const float*)d_in[0];
  const int*   ei    = (const int*)d_in[1];
  const float* emb_W = (const float*)d_in[3];
  const float* emb_b = (const float*)d_in[4];
  const float* Wl    = (const float*)d_in[5];
  const float* bl    = (const float*)d_in[6];
  const float* Wr    = (const float*)d_in[7];
  const float* br    = (const float*)d_in[8];
  const float* att   = (const float*)d_in[9];
  const float* cbias = (const float*)d_in[10];
  const float* p1W   = (const float*)d_in[11];
  const float* p1b   = (const float*)d_in[12];
  const float* p2W   = (const float*)d_in[13];
  const float* p2b   = (const float*)d_in[14];
  const float* p3W   = (const float*)d_in[15];
  const float* p3b   = (const float*)d_in[16];
  float* out = (float*)d_out;

  char* ws = (char*)d_ws;
  size_t o = 0;
  float* h0 = (float*)(ws + o); o += (size_t)NN * 128 * 4;
  float* h1 = (float*)(ws + o); o += (size_t)NN * 128 * 4;
  unsigned short* h_hl = (unsigned short*)(ws + o); o += (size_t)NN * 256 * 2;
  unsigned short* xl_bf = (unsigned short*)(ws + o); o += (size_t)NN * 512 * 2;
  unsigned short* xr_bf = (unsigned short*)(ws + o); o += (size_t)NN * 512 * 2;
  unsigned short* BT = (unsigned short*)(ws + o); o += (size_t)LAYERS * 1024 * 256 * 2;
  int* indptr = (int*)(ws + o); o += (((size_t)(NN + 1) * 4) + 255) / 256 * 256;
  int* counts = (int*)(ws + o); o += (((size_t)NN * 4) + 255) / 256 * 256;
  int* srcs   = (int*)(ws + o); o += (size_t)NE * 4;

  const int* esrc = ei;
  const int* edst = ei + NE;

  // CSR build
  hipMemsetAsync(counts, 0, (size_t)NN * 4, stream);
  hist_kernel<<<(NE + 255) / 256, 256, 0, stream>>>(edst, counts, NE);
  scan_kernel<<<1, 1024, 0, stream>>>(counts, indptr, NN);
  hipMemsetAsync(counts, 0, (size_t)NN * 4, stream);
  scatter_kernel<<<(NE + 255) / 256, 256, 0, stream>>>(esrc, edst, indptr, counts, srcs, NE);

  // weight prep: concat + split + transpose
  prep_w<<<(LAYERS * 1024 * 128) / 256, 256, 0, stream>>>(Wl, Wr, BT);

  // embedding (fp32) + hi/lo split fused
  gemm_bias<1, 1><<<dim3(2, (NN + 63) / 64), 256, 0, stream>>>(
      x, emb_W, emb_b, h0, h_hl, NN, 64, 128);

  float* hc = h0;
  float* hn = h1;
  for (int l = 0; l < LAYERS; ++l) {
    mfma_gemm_pers<<<512, 256, 0, stream>>>(
        h_hl, BT + (size_t)l * 1024 * 256,
        bl + (size_t)l * 512, br + (size_t)l * 512, xl_bf, xr_bf, NN);
    gat_aggregate<<<(NN + 3) / 4, 256, 0, stream>>>(
        xl_bf, xr_bf, indptr, srcs, att + (size_t)l * 512, cbias + (size_t)l * 128,
        hc, hn, h_hl, (l < LAYERS - 1) ? 1 : 0);
    float* t = hc; hc = hn; hn = t;
  }

  // predictor (fp32), reuse xl/xr space
  float* z1 = (float*)xl_bf;
  float* z2 = (float*)xr_bf;
  gemm_bias<1, 0><<<dim3(2, (NN + 63) / 64), 256, 0, stream>>>(
      hc, p1W, p1b, z1, (unsigned short*)0, NN, 128, 128);
  gemm_bias<1, 0><<<dim3(1, (NN + 63) / 64), 256, 0, stream>>>(
      z1, p2W, p2b, z2, (unsigned short*)0, NN, 128, 64);
  predictor_final<<<(NN + 3) / 4, 256, 0, stream>>>(z2, p3W, p3b, out, NN);
}

// Round 15
// 786.625 us; speedup vs baseline: 1.5922x; 1.0982x over previous
//
#include <hip/hip_runtime.h>
#include <math.h>

#define NN 50000
#define NE 800000
#define F_IN 64
#define HID 128
#define HEADS 4
#define LAYERS 3

typedef __attribute__((ext_vector_type(8))) short bf16x8;
typedef __attribute__((ext_vector_type(8))) unsigned short ushort8;
typedef __attribute__((ext_vector_type(4))) float f32x4;
typedef __attribute__((ext_vector_type(4))) unsigned int u32x4;
typedef __attribute__((ext_vector_type(2))) unsigned int u32x2;

__device__ __forceinline__ float b2f(unsigned short u) {
  return __builtin_bit_cast(float, ((unsigned int)u) << 16);
}
__device__ __forceinline__ unsigned short f2bf(float f) {
  unsigned int u = __builtin_bit_cast(unsigned int, f);
  u = (u + 0x7FFFu + ((u >> 16) & 1u)) >> 16;
  return (unsigned short)u;
}
__device__ __forceinline__ float bitf(unsigned int u) {
  return __builtin_bit_cast(float, u);
}

__device__ __forceinline__ void gload16(const void* g, void* l) {
  __builtin_amdgcn_global_load_lds(
      (const __attribute__((address_space(1))) unsigned int*)g,
      (__attribute__((address_space(3))) unsigned int*)l, 16, 0, 0);
}

// ---------------- CSR build ----------------

__global__ void hist_kernel(const int* __restrict__ dst, int* __restrict__ counts, int E) {
  int e = blockIdx.x * blockDim.x + threadIdx.x;
  if (e < E) atomicAdd(&counts[dst[e]], 1);
}

// 3-kernel scan: per-chunk exclusive scan + chunk sums -> offset scan -> add offsets
__global__ void scan1_kernel(const int* __restrict__ counts, int* __restrict__ indptr,
                             int* __restrict__ bsum, int n) {
  __shared__ int buf[1024];
  int tid = threadIdx.x;
  int i = blockIdx.x * 1024 + tid;
  int v = (i < n) ? counts[i] : 0;
  buf[tid] = v;
  __syncthreads();
  for (int off = 1; off < 1024; off <<= 1) {
    int t = (tid >= off) ? buf[tid - off] : 0;
    __syncthreads();
    buf[tid] += t;
    __syncthreads();
  }
  if (i < n) indptr[i] = buf[tid] - v;   // exclusive within chunk
  if (tid == 1023) bsum[blockIdx.x] = buf[1023];
}

__global__ void scan2_kernel(int* __restrict__ bsum, int* __restrict__ boff,
                             int nb, int* __restrict__ indptr, int n) {
  if (threadIdx.x == 0 && blockIdx.x == 0) {
    int s = 0;
    for (int c = 0; c < nb; ++c) { boff[c] = s; s += bsum[c]; }
    indptr[n] = s;
  }
}

__global__ void scan3_kernel(int* __restrict__ indptr, const int* __restrict__ boff, int n) {
  int i = blockIdx.x * 1024 + threadIdx.x;
  if (i < n) indptr[i] += boff[blockIdx.x];
}

__global__ void scatter_kernel(const int* __restrict__ src, const int* __restrict__ dst,
                               const int* __restrict__ indptr, int* __restrict__ fill,
                               int* __restrict__ srcs, int E) {
  int e = blockIdx.x * blockDim.x + threadIdx.x;
  if (e < E) {
    int d = dst[e];
    int pos = atomicAdd(&fill[d], 1);
    srcs[indptr[d] + pos] = src[e];
  }
}

// ---------------- weight prep: concat Wl|Wr, split hi/lo, transpose -> BT[L][1024][256] ----------------

__global__ void prep_w(const float* __restrict__ Wl, const float* __restrict__ Wr,
                       unsigned short* __restrict__ BT) {
  int id = blockIdx.x * 256 + threadIdx.x;   // < LAYERS*1024*128
  int l = id >> 17;
  int rem = id & 131071;
  int n = rem >> 7;
  int k = rem & 127;
  float v = (n < 512) ? Wl[((size_t)l * 128 + k) * 512 + n]
                      : Wr[((size_t)l * 128 + k) * 512 + (n - 512)];
  unsigned short h = f2bf(v);
  unsigned short lo = f2bf(v - b2f(h));
  size_t base = (size_t)(l * 1024 + n) * 256 + k;
  BT[base] = h;
  BT[base + 128] = lo;
}

// ---------------- MFMA GEMM: A via global_load_lds double-buffer, B in registers (r14 proven) ----------------

#define MT64 ((NN + 63) / 64)

__global__ void __launch_bounds__(256)
mfma_gemm_pers(const unsigned short* __restrict__ AHL, const unsigned short* __restrict__ BT,
               const float* __restrict__ bias_l, const float* __restrict__ bias_r,
               unsigned short* __restrict__ XL, unsigned short* __restrict__ XR, int M) {
  __shared__ unsigned short sA[2 * 16384];   // 2 x (64 rows x 256 ushorts)

  int bid = blockIdx.x;
  int wg = (bid & 7) * 64 + (bid >> 3);
  int ntile = wg & 7;
  int mgroup = wg >> 3;
  int n0 = ntile * 128;

  int T = threadIdx.x;
  int wv = T >> 6, lane = T & 63;
  int r15 = lane & 15;
  int kslot = lane >> 4;
  int rx = lane & 7;

  int srow = T >> 5;
  int sw16 = (T & 31) ^ (srow & 7);

  bf16x8 wbh[4][2], wbl[4][2];
#pragma unroll
  for (int ks = 0; ks < 4; ++ks)
#pragma unroll
    for (int fw = 0; fw < 2; ++fw) {
      int row = n0 + wv * 32 + fw * 16 + r15;
      size_t idx = (size_t)row * 256 + ks * 32 + kslot * 8;
      wbh[ks][fw] = *(const bf16x8*)&BT[idx];
      wbl[ks][fw] = *(const bf16x8*)&BT[idx + 128];
    }

  unsigned short* Xout = (ntile < 4) ? XL : XR;
  const float* bias_sel = (ntile < 4) ? bias_l : bias_r;
  int ncol0 = (n0 & 511) + wv * 32;
  f32x4 bv[2];
#pragma unroll
  for (int fw = 0; fw < 2; ++fw)
    bv[fw] = *(const f32x4*)&bias_sel[ncol0 + fw * 16 + kslot * 4];

  int abase[4];
#pragma unroll
  for (int fa = 0; fa < 4; ++fa) abase[fa] = (fa * 16 + r15) * 256;

  {
    int m0 = mgroup * 64;
#pragma unroll
    for (int R = 0; R < 8; ++R) {
      int grow = m0 + R * 8 + srow;
      if (grow >= M) grow = M - 1;
      gload16(AHL + (size_t)grow * 256 + sw16 * 8, sA + R * 2048 + wv * 512);
    }
  }
  __syncthreads();

  int cur = 0;
  for (int mt = mgroup; mt < MT64; mt += 64) {
    int m0 = mt * 64;
    int nmt = mt + 64;
    if (nmt < MT64) {
      int nm0 = nmt * 64;
      int obuf = (cur ^ 1) * 16384;
#pragma unroll
      for (int R = 0; R < 8; ++R) {
        int grow = nm0 + R * 8 + srow;
        if (grow >= M) grow = M - 1;
        gload16(AHL + (size_t)grow * 256 + sw16 * 8, sA + obuf + R * 2048 + wv * 512);
      }
    }

    const unsigned short* Ab = sA + cur * 16384;
    f32x4 acc[2][4];
#pragma unroll
    for (int i = 0; i < 2; ++i)
#pragma unroll
      for (int j = 0; j < 4; ++j) acc[i][j] = (f32x4)0.f;

#pragma unroll
    for (int ks = 0; ks < 4; ++ks) {
      int shi = ((ks * 4 + kslot) ^ rx) * 8;
      int slo = ((16 + ks * 4 + kslot) ^ rx) * 8;
      bf16x8 fah[4], fal[4];
#pragma unroll
      for (int fa = 0; fa < 4; ++fa) {
        fah[fa] = *(const bf16x8*)&Ab[abase[fa] + shi];
        fal[fa] = *(const bf16x8*)&Ab[abase[fa] + slo];
      }
#pragma unroll
      for (int fw = 0; fw < 2; ++fw)
#pragma unroll
        for (int fa = 0; fa < 4; ++fa) {
          f32x4 c = acc[fw][fa];
          c = __builtin_amdgcn_mfma_f32_16x16x32_bf16(wbl[ks][fw], fah[fa], c, 0, 0, 0);
          c = __builtin_amdgcn_mfma_f32_16x16x32_bf16(wbh[ks][fw], fal[fa], c, 0, 0, 0);
          c = __builtin_amdgcn_mfma_f32_16x16x32_bf16(wbh[ks][fw], fah[fa], c, 0, 0, 0);
          acc[fw][fa] = c;
        }
    }

#pragma unroll
    for (int fa = 0; fa < 4; ++fa) {
      int row = m0 + fa * 16 + r15;
      if (row < M) {
#pragma unroll
        for (int fw = 0; fw < 2; ++fw) {
          int col = ncol0 + fw * 16 + kslot * 4;
          f32x4 v = acc[fw][fa];
          unsigned int u0 = (unsigned int)f2bf(v[0] + bv[fw][0]) |
                            ((unsigned int)f2bf(v[1] + bv[fw][1]) << 16);
          unsigned int u1 = (unsigned int)f2bf(v[2] + bv[fw][2]) |
                            ((unsigned int)f2bf(v[3] + bv[fw][3]) << 16);
          u32x2 o; o[0] = u0; o[1] = u1;
          *(u32x2*)&Xout[(size_t)row * 512 + col] = o;
        }
      }
    }
    __syncthreads();
    cur ^= 1;
  }
}

// ---------------- fp32 tiled GEMM: C = act(A @ B + bias), optional hi/lo split output ----------------

template <int ACT, int SPLIT>
__global__ void __launch_bounds__(256)
gemm_bias(const float* __restrict__ A, const float* __restrict__ B,
          const float* __restrict__ bias, float* __restrict__ C,
          unsigned short* __restrict__ Chl,
          int M, int K, int Nc) {
  __shared__ float As[16][68];
  __shared__ float Bs[16][68];
  int tid = threadIdx.x;
  int tx = tid & 15, ty = tid >> 4;
  int m0 = blockIdx.y * 64;
  int n0 = blockIdx.x * 64;

  int arow = tid >> 2;
  int acol = (tid & 3) * 4;
  int brow = tid >> 4;
  int bcol = (tid & 15) * 4;

  float acc[4][4];
#pragma unroll
  for (int i = 0; i < 4; ++i)
#pragma unroll
    for (int j = 0; j < 4; ++j) acc[i][j] = 0.f;

  for (int k0 = 0; k0 < K; k0 += 16) {
    float4 av = make_float4(0.f, 0.f, 0.f, 0.f);
    if (m0 + arow < M) av = *(const float4*)&A[(size_t)(m0 + arow) * K + k0 + acol];
    As[acol + 0][arow] = av.x;
    As[acol + 1][arow] = av.y;
    As[acol + 2][arow] = av.z;
    As[acol + 3][arow] = av.w;
    float4 bvv = *(const float4*)&B[(size_t)(k0 + brow) * Nc + n0 + bcol];
    *(float4*)&Bs[brow][bcol] = bvv;
    __syncthreads();
#pragma unroll
    for (int k = 0; k < 16; ++k) {
      float4 a = *(const float4*)&As[k][ty * 4];
      float4 b = *(const float4*)&Bs[k][tx * 4];
      acc[0][0] += a.x * b.x; acc[0][1] += a.x * b.y; acc[0][2] += a.x * b.z; acc[0][3] += a.x * b.w;
      acc[1][0] += a.y * b.x; acc[1][1] += a.y * b.y; acc[1][2] += a.y * b.z; acc[1][3] += a.y * b.w;
      acc[2][0] += a.z * b.x; acc[2][1] += a.z * b.y; acc[2][2] += a.z * b.z; acc[2][3] += a.z * b.w;
      acc[3][0] += a.w * b.x; acc[3][1] += a.w * b.y; acc[3][2] += a.w * b.z; acc[3][3] += a.w * b.w;
    }
    __syncthreads();
  }

#pragma unroll
  for (int i = 0; i < 4; ++i) {
    int row = m0 + ty * 4 + i;
    if (row < M) {
#pragma unroll
      for (int j = 0; j < 4; ++j) {
        int col = n0 + tx * 4 + j;
        float v = acc[i][j] + bias[col];
        if (ACT) v = fmaxf(v, 0.f);
        C[(size_t)row * Nc + col] = v;
        if (SPLIT) {
          unsigned short hh = f2bf(v);
          Chl[(size_t)row * 256 + col] = hh;
          Chl[(size_t)row * 256 + 128 + col] = f2bf(v - b2f(hh));
        }
      }
    }
  }
}

// ---------------- GATv2 edge phase: 1 wave per node, 8 edges in flight, xf in registers ----------------

__global__ void __launch_bounds__(256)
gat_aggregate(const unsigned short* __restrict__ xl, const unsigned short* __restrict__ xr,
              const int* __restrict__ indptr, const int* __restrict__ srcs,
              const float* __restrict__ att, const float* __restrict__ conv_bias,
              const float* __restrict__ h_in, float* __restrict__ h_out,
              unsigned short* __restrict__ o_hl, int write_split) {
  int node = blockIdx.x * 4 + (threadIdx.x >> 6);
  if (node >= NN) return;
  int lane = threadIdx.x & 63;
  int h = lane >> 4, g = lane & 15;
  int ch = h * 128 + g * 8;

  float a1[8], a2[8], xr8[8];
  {
    f32x4 t0 = *(const f32x4*)(att + ch);
    f32x4 t1 = *(const f32x4*)(att + ch + 4);
#pragma unroll
    for (int j = 0; j < 4; ++j) { a1[j] = 0.6f * t0[j]; a2[j] = 0.4f * t0[j]; }
#pragma unroll
    for (int j = 0; j < 4; ++j) { a1[4 + j] = 0.6f * t1[j]; a2[4 + j] = 0.4f * t1[j]; }
    u32x4 q = __builtin_nontemporal_load((const u32x4*)&xr[(size_t)node * 512 + ch]);
#pragma unroll
    for (int j = 0; j < 4; ++j) {
      xr8[2 * j] = bitf(q[j] << 16);
      xr8[2 * j + 1] = bitf(q[j] & 0xFFFF0000u);
    }
  }
  float base1 = 0.f;
#pragma unroll
  for (int j = 0; j < 8; ++j) base1 = fmaf(a1[j], xr8[j], base1);

  float acc[8];
#pragma unroll
  for (int j = 0; j < 8; ++j) acc[j] = 0.f;
  float s_run = 0.f;

  int beg = indptr[node];
  int deg = indptr[node + 1] - beg;

  for (int s0 = 0; s0 < deg; s0 += 8) {
    // batch-issue 8 gathers
    u32x4 q[8];
    int valid = deg - s0;
#pragma unroll
    for (int t = 0; t < 8; ++t) {
      int slot = s0 + t;
      int s = (slot < deg) ? srcs[beg + slot] : srcs[beg];
      q[t] = *(const u32x4*)&xl[(size_t)s * 512 + ch];
    }
    // extract once into registers (q[t] dead after)
    float xf[8][8];
#pragma unroll
    for (int t = 0; t < 8; ++t)
#pragma unroll
      for (int j = 0; j < 4; ++j) {
        xf[t][2 * j] = bitf(q[t][j] << 16);
        xf[t][2 * j + 1] = bitf(q[t][j] & 0xFFFF0000u);
      }
    // scores (fabsf folds into fma input modifier)
    float p[8];
#pragma unroll
    for (int t = 0; t < 8; ++t) {
      float pp = base1;
#pragma unroll
      for (int j = 0; j < 8; ++j) {
        pp = fmaf(a1[j], xf[t][j], pp);
        pp = fmaf(a2[j], fabsf(xf[t][j] + xr8[j]), pp);
      }
      p[t] = pp;
    }
#pragma unroll
    for (int t = 0; t < 8; ++t) {
#pragma unroll
      for (int off = 1; off < 16; off <<= 1) p[t] += __shfl_xor(p[t], off);
    }
    float w[8];
#pragma unroll
    for (int t = 0; t < 8; ++t)
      w[t] = (t < valid) ? __expf(p[t]) : 0.f;
#pragma unroll
    for (int t = 0; t < 8; ++t) s_run += w[t];
    // pure-fma accumulate
#pragma unroll
    for (int j = 0; j < 8; ++j) {
      float v = acc[j];
#pragma unroll
      for (int t = 0; t < 8; ++t) v = fmaf(w[t], xf[t][j], v);
      acc[j] = v;
    }
  }

  float inv = 1.f / fmaxf(s_run, 1e-16f);
  float v[8];
#pragma unroll
  for (int j = 0; j < 8; ++j) v[j] = acc[j] * inv;
#pragma unroll
  for (int j = 0; j < 8; ++j) v[j] += __shfl_xor(v[j], 16);
#pragma unroll
  for (int j = 0; j < 8; ++j) v[j] += __shfl_xor(v[j], 32);

  if (h == 0) {
    int c0 = g * 8;
    const float* hip_ = h_in + (size_t)node * 128 + c0;
    f32x4 hi0 = __builtin_nontemporal_load((const f32x4*)hip_);
    f32x4 hi1 = __builtin_nontemporal_load((const f32x4*)(hip_ + 4));
    f32x4 cb0 = *(const f32x4*)(conv_bias + c0);
    f32x4 cb1 = *(const f32x4*)(conv_bias + c0 + 4);
    float rr[8];
#pragma unroll
    for (int j = 0; j < 4; ++j) rr[j] = fmaxf(fmaf(v[j], 0.25f, cb0[j] + hi0[j]), 0.f);
#pragma unroll
    for (int j = 0; j < 4; ++j) rr[4 + j] = fmaxf(fmaf(v[4 + j], 0.25f, cb1[j] + hi1[j]), 0.f);
    f32x4 o0, o1;
#pragma unroll
    for (int j = 0; j < 4; ++j) { o0[j] = rr[j]; o1[j] = rr[4 + j]; }
    float* hop = h_out + (size_t)node * 128 + c0;
    __builtin_nontemporal_store(o0, (f32x4*)hop);
    __builtin_nontemporal_store(o1, (f32x4*)(hop + 4));
    if (write_split) {
      ushort8 hv, lv;
#pragma unroll
      for (int j = 0; j < 8; ++j) {
        unsigned short hh = f2bf(rr[j]);
        hv[j] = hh;
        lv[j] = f2bf(rr[j] - b2f(hh));
      }
      __builtin_nontemporal_store(hv, (ushort8*)&o_hl[(size_t)node * 256 + c0]);
      __builtin_nontemporal_store(lv, (ushort8*)&o_hl[(size_t)node * 256 + 128 + c0]);
    }
  }
}

// ---------------- final: score = clip(z2 @ p3_W + p3_b) ----------------

__global__ void __launch_bounds__(256)
predictor_final(const float* __restrict__ z2, const float* __restrict__ w3,
                const float* __restrict__ b3, float* __restrict__ out, int n) {
  int node = (blockIdx.x << 2) + (threadIdx.x >> 6);
  int lane = threadIdx.x & 63;
  if (node >= n) return;
  float v = z2[(size_t)node * 64 + lane] * w3[lane];
#pragma unroll
  for (int off = 32; off > 0; off >>= 1) v += __shfl_xor(v, off);
  if (lane == 0) {
    float s = v + b3[0];
    s = fminf(fmaxf(s, -15.f), 15.f);
    out[node] = s;
  }
}

// ---------------- launch ----------------

extern "C" void kernel_launch(void* const* d_in, const int* in_sizes, int n_in,
                              void* d_out, int out_size, void* d_ws, size_t ws_size,
                              hipStream_t stream) {
  const float* x     = (const float*)d_in[0];
  const int*   ei    = (const int*)d_in[1];
  const float* emb_W = (const float*)d_in[3];
  const float* emb_b = (const float*)d_in[4];
  const float* Wl    = (const float*)d_in[5];
  const float* bl    = (const float*)d_in[6];
  const float* Wr    = (const float*)d_in[7];
  const float* br    = (const float*)d_in[8];
  const float* att   = (const float*)d_in[9];
  const float* cbias = (const float*)d_in[10];
  const float* p1W   = (const float*)d_in[11];
  const float* p1b   = (const float*)d_in[12];
  const float* p2W   = (const float*)d_in[13];
  const float* p2b   = (const float*)d_in[14];
  const float* p3W   = (const float*)d_in[15];
  const float* p3b   = (const float*)d_in[16];
  float* out = (float*)d_out;

  char* ws = (char*)d_ws;
  size_t o = 0;
  float* h0 = (float*)(ws + o); o += (size_t)NN * 128 * 4;
  float* h1 = (float*)(ws + o); o += (size_t)NN * 128 * 4;
  unsigned short* h_hl = (unsigned short*)(ws + o); o += (size_t)NN * 256 * 2;
  unsigned short* xl_bf = (unsigned short*)(ws + o); o += (size_t)NN * 512 * 2;
  unsigned short* xr_bf = (unsigned short*)(ws + o); o += (size_t)NN * 512 * 2;
  unsigned short* BT = (unsigned short*)(ws + o); o += (size_t)LAYERS * 1024 * 256 * 2;
  int* indptr = (int*)(ws + o); o += (((size_t)(NN + 1) * 4) + 255) / 256 * 256;
  int* counts = (int*)(ws + o); o += (((size_t)NN * 4) + 255) / 256 * 256;
  int* bsum = (int*)(ws + o); o += 256;
  int* boff = (int*)(ws + o); o += 256;
  int* srcs   = (int*)(ws + o); o += (size_t)NE * 4;

  const int* esrc = ei;
  const int* edst = ei + NE;
  int nb = (NN + 1023) / 1024;

  // CSR build (parallel 3-kernel scan)
  hipMemsetAsync(counts, 0, (size_t)NN * 4, stream);
  hist_kernel<<<(NE + 255) / 256, 256, 0, stream>>>(edst, counts, NE);
  scan1_kernel<<<nb, 1024, 0, stream>>>(counts, indptr, bsum, NN);
  scan2_kernel<<<1, 64, 0, stream>>>(bsum, boff, nb, indptr, NN);
  scan3_kernel<<<nb, 1024, 0, stream>>>(indptr, boff, NN);
  hipMemsetAsync(counts, 0, (size_t)NN * 4, stream);
  scatter_kernel<<<(NE + 255) / 256, 256, 0, stream>>>(esrc, edst, indptr, counts, srcs, NE);

  // weight prep: concat + split + transpose
  prep_w<<<(LAYERS * 1024 * 128) / 256, 256, 0, stream>>>(Wl, Wr, BT);

  // embedding (fp32) + hi/lo split fused
  gemm_bias<1, 1><<<dim3(2, (NN + 63) / 64), 256, 0, stream>>>(
      x, emb_W, emb_b, h0, h_hl, NN, 64, 128);

  float* hc = h0;
  float* hn = h1;
  for (int l = 0; l < LAYERS; ++l) {
    mfma_gemm_pers<<<512, 256, 0, stream>>>(
        h_hl, BT + (size_t)l * 1024 * 256,
        bl + (size_t)l * 512, br + (size_t)l * 512, xl_bf, xr_bf, NN);
    gat_aggregate<<<(NN + 3) / 4, 256, 0, stream>>>(
        xl_bf, xr_bf, indptr, srcs, att + (size_t)l * 512, cbias + (size_t)l * 128,
        hc, hn, h_hl, (l < LAYERS - 1) ? 1 : 0);
    float* t = hc; hc = hn; hn = t;
  }

  // predictor (fp32), reuse xl/xr space
  float* z1 = (float*)xl_bf;
  float* z2 = (float*)xr_bf;
  gemm_bias<1, 0><<<dim3(2, (NN + 63) / 64), 256, 0, stream>>>(
      hc, p1W, p1b, z1, (unsigned short*)0, NN, 128, 128);
  gemm_bias<1, 0><<<dim3(1, (NN + 63) / 64), 256, 0, stream>>>(
      z1, p2W, p2b, z2, (unsigned short*)0, NN, 128, 64);
  predictor_final<<<(NN + 3) / 4, 256, 0, stream>>>(z2, p3W, p3b, out, NN);
}